// Round 7
// baseline (167.688 us; speedup 1.0000x reference)
//
#include <hip/hip_runtime.h>

#define V_IN 40962
#define V_OUT 163842
#define NCH 64
#define CTOT 256

typedef float    f2 __attribute__((ext_vector_type(2)));
typedef float    f4 __attribute__((ext_vector_type(4)));
typedef _Float16 h2 __attribute__((ext_vector_type(2)));
typedef _Float16 h4 __attribute__((ext_vector_type(4)));

// ---------------- transpose+downcast: x[2][256][V_IN] f32 -> xT[2][V_IN][256] fp16 ----------------
__global__ __launch_bounds__(256) void transpose_k(const float* __restrict__ x,
                                                   _Float16* __restrict__ xT) {
    __shared__ float tile[64][65];   // [v][c]
    const int b  = blockIdx.z;
    const int v0 = blockIdx.x * 64;
    const int c0 = blockIdx.y * 64;
    const int t  = threadIdx.x;
    const int i  = t & 15;
    const int s  = t >> 4;           // 0..15
#pragma unroll
    for (int p = 0; p < 4; ++p) {
        int c = s + 16 * p;
        int v = 4 * i;
        f4 val = {0.f, 0.f, 0.f, 0.f};
        const float* src = x + ((size_t)b * CTOT + c0 + c) * V_IN + v0 + v;
        if (v0 + v + 3 < V_IN) {
            val = __builtin_nontemporal_load((const f4*)src);
        } else {
            if (v0 + v     < V_IN) val.x = src[0];
            if (v0 + v + 1 < V_IN) val.y = src[1];
            if (v0 + v + 2 < V_IN) val.z = src[2];
            if (v0 + v + 3 < V_IN) val.w = src[3];
        }
        tile[v    ][c] = val.x;
        tile[v + 1][c] = val.y;
        tile[v + 2][c] = val.z;
        tile[v + 3][c] = val.w;
    }
    __syncthreads();
#pragma unroll
    for (int p = 0; p < 4; ++p) {
        int v = s + 16 * p;
        if (v0 + v < V_IN) {
            h4 val;
            val.x = (_Float16)tile[v][4 * i];
            val.y = (_Float16)tile[v][4 * i + 1];
            val.z = (_Float16)tile[v][4 * i + 2];
            val.w = (_Float16)tile[v][4 * i + 3];
            *(h4*)(xT + ((size_t)b * V_IN + v0 + v) * CTOT + c0 + 4 * i) = val;
        }
    }
}

// ---------------- per-output attention math, NO max-subtraction ----------------
// |s| <= 8 * max|x| * 0.125 <= ~5.6  ->  exp2 arg = s*log2(e)/8 in [-1.01, 1.01]: safe.
__device__ __forceinline__ float attn_one(const float vals[8], const f2 (&cs2)[8][4]) {
    f2 s2[4];
#pragma unroll
    for (int j = 0; j < 4; ++j) s2[j] = cs2[0][j] * vals[0];
#pragma unroll
    for (int k = 1; k < 8; ++k) {
        f2 vk = {vals[k], vals[k]};
#pragma unroll
        for (int j = 0; j < 4; ++j)
            s2[j] = __builtin_elementwise_fma(vk, cs2[k][j], s2[j]);
    }
    const float C = 0.18033688011112042f;   // log2(e)/8
    f2 C2 = {C, C};
    f2 sum2 = {0.f, 0.f}, num2 = {0.f, 0.f};
#pragma unroll
    for (int j = 0; j < 4; ++j) {
        f2 tt = s2[j] * C2;
        f2 e;
        e.x = __builtin_amdgcn_exp2f(tt.x);
        e.y = __builtin_amdgcn_exp2f(tt.y);
        sum2 += e;
        f2 v2 = {vals[2 * j], vals[2 * j + 1]};
        num2 = __builtin_elementwise_fma(v2, e, num2);
    }
    float sum = sum2.x + sum2.y;
    float num = num2.x + num2.y;
    return num * __builtin_amdgcn_rcpf(sum);
}

__device__ __forceinline__ void unpack2(const h4& a0, const h4& a1, float (&vals)[8]) {
    vals[0] = (float)a0.x; vals[1] = (float)a1.x;
    vals[2] = (float)a0.y; vals[3] = (float)a1.y;
    vals[4] = (float)a0.z; vals[5] = (float)a1.z;
    vals[6] = (float)a0.w; vals[7] = (float)a1.w;
}

// ---------------- fused gather + attn + softmax + weighted sum ----------------
// Block = one 64-v tile, all 64 cgroups x both b. lane = cgroup, wave parity = v stripe.
template <int DIRECT>
__global__ __launch_bounds__(256) void fused_k(const _Float16* __restrict__ xsrc16,
                                               const float* __restrict__ xsrc32,
                                               const float* __restrict__ coeffs,
                                               const int* __restrict__ map,
                                               float* __restrict__ out) {
    __shared__ _Float16 otile[2][NCH][66];   // 66 halves/row = 132B = 33 dwords (odd -> no write conflicts)
    __shared__ int      jmap[128];

    const int tid    = threadIdx.x;
    const int lane   = tid & 63;
    const int w      = tid >> 6;
    const int b      = w >> 1;
    const int parity = w & 1;
    const int vbase  = blockIdx.x * 64;
    const bool full  = (vbase + 64 <= V_OUT);

    if (tid < 128) {
        int gi = vbase * 2 + tid;
        jmap[tid] = (gi < 2 * V_OUT) ? map[gi] : 0;
    }

    // wave-uniform coeff loads -> SGPRs
    f2 cs2[8][4];
#pragma unroll
    for (int k = 0; k < 8; ++k)
#pragma unroll
        for (int j = 0; j < 4; ++j)
            cs2[k][j] = *(const f2*)(coeffs + k * 8 + 2 * j);

    __syncthreads();

    const int c = lane;
    const _Float16* xb = xsrc16 + (size_t)b * V_IN * CTOT + 4 * c;

    if (full && !DIRECT) {
        // 4-deep software pipeline, fully unrolled => static register indexing
        h4 Pa[4], Pb[4];
#pragma unroll
        for (int q = 0; q < 4; ++q) {
            int2 jj = *(const int2*)&jmap[2 * (parity + 2 * q)];
            Pa[q] = *(const h4*)(xb + (size_t)jj.x * CTOT);
            Pb[q] = *(const h4*)(xb + (size_t)jj.y * CTOT);
        }
#pragma unroll
        for (int g = 0; g < 8; ++g) {
#pragma unroll
            for (int q = 0; q < 4; ++q) {
                const int i  = 4 * g + q;
                const int vl = parity + 2 * i;
                float vals[8];
                unpack2(Pa[q], Pb[q], vals);
                otile[b][c][vl] = (_Float16)attn_one(vals, cs2);
                // prefetch iteration i+4 (wraps harmlessly on the last group)
                const int ii = (i + 4) & 31;
                int2 jj = *(const int2*)&jmap[2 * (parity + 2 * ii)];
                Pa[q] = *(const h4*)(xb + (size_t)jj.x * CTOT);
                Pb[q] = *(const h4*)(xb + (size_t)jj.y * CTOT);
            }
        }
    } else {
        for (int i = 0; i < 32; ++i) {
            const int vl = parity + 2 * i;
            float r = 0.f;
            if (vbase + vl < V_OUT) {
                const int j0 = jmap[2 * vl];
                const int j1 = jmap[2 * vl + 1];
                float vals[8];
                if (DIRECT) {
#pragma unroll
                    for (int e = 0; e < 4; ++e) {
                        vals[2 * e]     = xsrc32[((size_t)b * CTOT + 4 * c + e) * V_IN + j0];
                        vals[2 * e + 1] = xsrc32[((size_t)b * CTOT + 4 * c + e) * V_IN + j1];
                    }
                } else {
                    h4 a0 = *(const h4*)(xb + (size_t)j0 * CTOT);
                    h4 a1 = *(const h4*)(xb + (size_t)j1 * CTOT);
                    unpack2(a0, a1, vals);
                }
                r = attn_one(vals, cs2);
            }
            otile[b][c][vl] = (_Float16)r;
        }
    }
    __syncthreads();

    // ---------------- write-out: 128 rows x 64 v, f4 nontemporal ----------------
    const int rw  = tid >> 2;        // 0..63
    const int seg = tid & 3;         // 16-v segment
    if (full) {
#pragma unroll
        for (int it = 0; it < 2; ++it) {
            const int r  = rw + 64 * it;          // 0..127
            const int bb = r >> 6, cc = r & 63;
            const _Float16* src = &otile[bb][cc][seg * 16];
            float* op = out + ((size_t)bb * NCH + cc) * V_OUT + vbase + seg * 16;
#pragma unroll
            for (int u = 0; u < 4; ++u) {
                h2 lo = *(const h2*)(src + 4 * u);
                h2 hi = *(const h2*)(src + 4 * u + 2);
                f4 val = {(float)lo.x, (float)lo.y, (float)hi.x, (float)hi.y};
                __builtin_nontemporal_store(val, (f4*)(op + 4 * u));
            }
        }
    } else {
#pragma unroll
        for (int it = 0; it < 2; ++it) {
            const int r  = rw + 64 * it;
            const int bb = r >> 6, cc = r & 63;
            for (int u = 0; u < 16; ++u) {
                int v = vbase + seg * 16 + u;
                if (v < V_OUT)
                    out[((size_t)bb * NCH + cc) * V_OUT + v] = (float)otile[bb][cc][seg * 16 + u];
            }
        }
    }
}

extern "C" void kernel_launch(void* const* d_in, const int* in_sizes, int n_in,
                              void* d_out, int out_size, void* d_ws, size_t ws_size,
                              hipStream_t stream) {
    const float* x      = (const float*)d_in[0];
    const float* coeffs = (const float*)d_in[1];
    const int*   map    = (const int*)d_in[2];
    float*       out    = (float*)d_out;

    const size_t xT_bytes = (size_t)2 * V_IN * CTOT * sizeof(_Float16);
    const int nblocks = (V_OUT + 63) / 64;

    if (ws_size >= xT_bytes) {
        _Float16* xT = (_Float16*)d_ws;
        dim3 tgrid((V_IN + 63) / 64, CTOT / 64, 2);
        transpose_k<<<tgrid, dim3(256), 0, stream>>>(x, xT);
        fused_k<0><<<nblocks, 256, 0, stream>>>(xT, nullptr, coeffs, map, out);
    } else {
        fused_k<1><<<nblocks, 256, 0, stream>>>(nullptr, x, coeffs, map, out);
    }
}

// Round 8
// 115.737 us; speedup vs baseline: 1.4489x; 1.4489x over previous
//
#include <hip/hip_runtime.h>

#define V_IN 40962
#define V_OUT 163842
#define NCH 64
#define CTOT 256

typedef float    f2 __attribute__((ext_vector_type(2)));
typedef float    f4 __attribute__((ext_vector_type(4)));
typedef _Float16 h4 __attribute__((ext_vector_type(4)));

// ---------------- transpose+downcast: x[2][256][V_IN] f32 -> xT[2][V_IN][256] fp16 ----------------
__global__ __launch_bounds__(256) void transpose_k(const float* __restrict__ x,
                                                   _Float16* __restrict__ xT) {
    __shared__ float tile[64][65];   // [v][c]
    const int b  = blockIdx.z;
    const int v0 = blockIdx.x * 64;
    const int c0 = blockIdx.y * 64;
    const int t  = threadIdx.x;
    const int i  = t & 15;
    const int s  = t >> 4;           // 0..15
#pragma unroll
    for (int p = 0; p < 4; ++p) {
        int c = s + 16 * p;
        int v = 4 * i;
        f4 val = {0.f, 0.f, 0.f, 0.f};
        const float* src = x + ((size_t)b * CTOT + c0 + c) * V_IN + v0 + v;
        if (v0 + v + 3 < V_IN) {
            val = __builtin_nontemporal_load((const f4*)src);
        } else {
            if (v0 + v     < V_IN) val.x = src[0];
            if (v0 + v + 1 < V_IN) val.y = src[1];
            if (v0 + v + 2 < V_IN) val.z = src[2];
            if (v0 + v + 3 < V_IN) val.w = src[3];
        }
        tile[v    ][c] = val.x;
        tile[v + 1][c] = val.y;
        tile[v + 2][c] = val.z;
        tile[v + 3][c] = val.w;
    }
    __syncthreads();
#pragma unroll
    for (int p = 0; p < 4; ++p) {
        int v = s + 16 * p;
        if (v0 + v < V_IN) {
            h4 val;
            val.x = (_Float16)tile[v][4 * i];
            val.y = (_Float16)tile[v][4 * i + 1];
            val.z = (_Float16)tile[v][4 * i + 2];
            val.w = (_Float16)tile[v][4 * i + 3];
            *(h4*)(xT + ((size_t)b * V_IN + v0 + v) * CTOT + c0 + 4 * i) = val;
        }
    }
}

// ---------------- per-output attention math, NO max-subtraction ----------------
// |s| <= 8 * max|x| * 0.125 ~= 5.7 -> exp2 arg = s*log2(e)/8 in [-1.03, 1.03]: safe,
// and denominator >= 8*exp(-0.72) ~ 3.9 (no cancellation). Softmax is shift-invariant.
__device__ __forceinline__ float attn_one(const float vals[8], const f2 (&cs2)[8][4]) {
    f2 s2[4];
#pragma unroll
    for (int j = 0; j < 4; ++j) s2[j] = cs2[0][j] * vals[0];
#pragma unroll
    for (int k = 1; k < 8; ++k) {
        f2 vk = {vals[k], vals[k]};
#pragma unroll
        for (int j = 0; j < 4; ++j)
            s2[j] = __builtin_elementwise_fma(vk, cs2[k][j], s2[j]);
    }
    const float C = 0.18033688011112042f;   // log2(e)/8
    f2 C2 = {C, C};
    f2 sum2 = {0.f, 0.f}, num2 = {0.f, 0.f};
#pragma unroll
    for (int j = 0; j < 4; ++j) {
        f2 tt = s2[j] * C2;
        f2 e;
        e.x = __builtin_amdgcn_exp2f(tt.x);
        e.y = __builtin_amdgcn_exp2f(tt.y);
        sum2 += e;
        f2 v2 = {vals[2 * j], vals[2 * j + 1]};
        num2 = __builtin_elementwise_fma(v2, e, num2);
    }
    float sum = sum2.x + sum2.y;
    float num = num2.x + num2.y;
    return num * __builtin_amdgcn_rcpf(sum);
}

__device__ __forceinline__ void unpack2(const h4& a0, const h4& a1, float (&vals)[8]) {
    vals[0] = (float)a0.x; vals[1] = (float)a1.x;
    vals[2] = (float)a0.y; vals[3] = (float)a1.y;
    vals[4] = (float)a0.z; vals[5] = (float)a1.z;
    vals[6] = (float)a0.w; vals[7] = (float)a1.w;
}

// ---------------- fused gather + attn + softmax + weighted sum ----------------
// DIRECT=0: xsrc16 = xT[b][v_in][256] fp16.  DIRECT=1: fall back to raw f32 x.
template <int DIRECT>
__global__ __launch_bounds__(256) void fused_k(const _Float16* __restrict__ xsrc16,
                                               const float* __restrict__ xsrc32,
                                               const float* __restrict__ coeffs,
                                               const int* __restrict__ map,
                                               float* __restrict__ out) {
    __shared__ float otile[2][NCH][33];
    __shared__ int   jmap[128];

    const int tid    = threadIdx.x;
    const int lane   = tid & 63;
    const int w      = tid >> 6;
    const int b      = w >> 1;
    const int parity = w & 1;
    const int vbase  = blockIdx.x * 64;
    const bool full  = (vbase + 64 <= V_OUT);

    if (tid < 128) {
        int gi = vbase * 2 + tid;
        jmap[tid] = (gi < 2 * V_OUT) ? map[gi] : 0;
    }

    f2 cs2[8][4];
#pragma unroll
    for (int k = 0; k < 8; ++k)
#pragma unroll
        for (int j = 0; j < 4; ++j)
            cs2[k][j] = *(const f2*)(coeffs + k * 8 + 2 * j);

    __syncthreads();

    const int c = lane;
    const _Float16* xb = xsrc16 + (size_t)b * V_IN * CTOT + 4 * c;

    for (int h = 0; h < 2; ++h) {
        if (full && !DIRECT) {
            // prefetch-distance-2 pipeline: at compute(i), loads for i+1 and i+2 in flight
            const int vl0 = h * 32 + parity;
            int2 j01 = *(const int2*)&jmap[2 * vl0];
            h4 a0 = *(const h4*)(xb + (size_t)j01.x * CTOT);
            h4 a1 = *(const h4*)(xb + (size_t)j01.y * CTOT);
            int2 j23 = *(const int2*)&jmap[2 * (vl0 + 2)];
            h4 b0 = *(const h4*)(xb + (size_t)j23.x * CTOT);
            h4 b1 = *(const h4*)(xb + (size_t)j23.y * CTOT);
#pragma unroll 2
            for (int i = 0; i < 16; ++i) {
                h4 f0 = a0, f1 = a1;           // dummy defaults for tail
                if (i < 14) {
                    int2 jn = *(const int2*)&jmap[2 * (vl0 + 2 * (i + 2))];
                    f0 = *(const h4*)(xb + (size_t)jn.x * CTOT);
                    f1 = *(const h4*)(xb + (size_t)jn.y * CTOT);
                }
                float vals[8];
                unpack2(a0, a1, vals);
                otile[b][c][parity + 2 * i] = attn_one(vals, cs2);
                a0 = b0; a1 = b1;
                b0 = f0; b1 = f1;
            }
        } else {
            for (int i = 0; i < 16; ++i) {
                const int vh = parity + 2 * i;
                const int vl = h * 32 + vh;
                float r = 0.f;
                if (vbase + vl < V_OUT) {
                    const int j0 = jmap[2 * vl];
                    const int j1 = jmap[2 * vl + 1];
                    float vals[8];
                    if (DIRECT) {
#pragma unroll
                        for (int e = 0; e < 4; ++e) {
                            vals[2 * e]     = xsrc32[((size_t)b * CTOT + 4 * c + e) * V_IN + j0];
                            vals[2 * e + 1] = xsrc32[((size_t)b * CTOT + 4 * c + e) * V_IN + j1];
                        }
                    } else {
                        h4 a0 = *(const h4*)(xb + (size_t)j0 * CTOT);
                        h4 a1 = *(const h4*)(xb + (size_t)j1 * CTOT);
                        unpack2(a0, a1, vals);
                    }
                    r = attn_one(vals, cs2);
                }
                otile[b][c][vh] = r;
            }
        }
        __syncthreads();

        if (full) {
#pragma unroll
            for (int t2 = 0; t2 < 8; ++t2) {
                int rr = w * 32 + (lane >> 4) + 4 * t2;
                int bb = rr >> 6, cc = rr & 63;
                int vv = (lane & 15) * 2;
                f2 val = {otile[bb][cc][vv], otile[bb][cc][vv + 1]};
                __builtin_nontemporal_store(val,
                    (f2*)(out + ((size_t)bb * NCH + cc) * V_OUT + vbase + h * 32 + vv));
            }
        } else {
            for (int t2 = 0; t2 < 8; ++t2) {
                int rr = w * 32 + (lane >> 4) + 4 * t2;
                int bb = rr >> 6, cc = rr & 63;
                int vv = (lane & 15) * 2;
#pragma unroll
                for (int q = 0; q < 2; ++q) {
                    int v = vbase + h * 32 + vv + q;
                    if (v < V_OUT) out[((size_t)bb * NCH + cc) * V_OUT + v] = otile[bb][cc][vv + q];
                }
            }
        }
        __syncthreads();
    }
}

extern "C" void kernel_launch(void* const* d_in, const int* in_sizes, int n_in,
                              void* d_out, int out_size, void* d_ws, size_t ws_size,
                              hipStream_t stream) {
    const float* x      = (const float*)d_in[0];
    const float* coeffs = (const float*)d_in[1];
    const int*   map    = (const int*)d_in[2];
    float*       out    = (float*)d_out;

    const size_t xT_bytes = (size_t)2 * V_IN * CTOT * sizeof(_Float16);
    const int nblocks = (V_OUT + 63) / 64;

    if (ws_size >= xT_bytes) {
        _Float16* xT = (_Float16*)d_ws;
        dim3 tgrid((V_IN + 63) / 64, CTOT / 64, 2);
        transpose_k<<<tgrid, dim3(256), 0, stream>>>(x, xT);
        fused_k<0><<<nblocks, 256, 0, stream>>>(xT, nullptr, coeffs, map, out);
    } else {
        fused_k<1><<<nblocks, 256, 0, stream>>>(nullptr, x, coeffs, map, out);
    }
}

// Round 9
// 93.604 us; speedup vs baseline: 1.7915x; 1.2365x over previous
//
#include <hip/hip_runtime.h>

#define V_IN 40962
#define V_OUT 163842
#define NCH 64
#define CTOT 256
#define NSLICE 8   // (b:2) x (channel-quarter:4); one slice per XCD via bid&7

typedef float    f2 __attribute__((ext_vector_type(2)));
typedef float    f4 __attribute__((ext_vector_type(4)));
typedef _Float16 h4 __attribute__((ext_vector_type(4)));

// ---------------- transpose+downcast: x[2][256][V_IN] f32 -> xT[2][V_IN][256] fp16 ----------------
__global__ __launch_bounds__(256) void transpose_k(const float* __restrict__ x,
                                                   _Float16* __restrict__ xT) {
    __shared__ float tile[64][65];   // [v][c]
    const int b  = blockIdx.z;
    const int v0 = blockIdx.x * 64;
    const int c0 = blockIdx.y * 64;
    const int t  = threadIdx.x;
    const int i  = t & 15;
    const int s  = t >> 4;           // 0..15
#pragma unroll
    for (int p = 0; p < 4; ++p) {
        int c = s + 16 * p;
        int v = 4 * i;
        f4 val = {0.f, 0.f, 0.f, 0.f};
        const float* src = x + ((size_t)b * CTOT + c0 + c) * V_IN + v0 + v;
        if (v0 + v + 3 < V_IN) {
            val = __builtin_nontemporal_load((const f4*)src);
        } else {
            if (v0 + v     < V_IN) val.x = src[0];
            if (v0 + v + 1 < V_IN) val.y = src[1];
            if (v0 + v + 2 < V_IN) val.z = src[2];
            if (v0 + v + 3 < V_IN) val.w = src[3];
        }
        tile[v    ][c] = val.x;
        tile[v + 1][c] = val.y;
        tile[v + 2][c] = val.z;
        tile[v + 3][c] = val.w;
    }
    __syncthreads();
#pragma unroll
    for (int p = 0; p < 4; ++p) {
        int v = s + 16 * p;
        if (v0 + v < V_IN) {
            h4 val;
            val.x = (_Float16)tile[v][4 * i];
            val.y = (_Float16)tile[v][4 * i + 1];
            val.z = (_Float16)tile[v][4 * i + 2];
            val.w = (_Float16)tile[v][4 * i + 3];
            *(h4*)(xT + ((size_t)b * V_IN + v0 + v) * CTOT + c0 + 4 * i) = val;
        }
    }
}

// ---------------- per-output attention math, NO max-subtraction ----------------
// |s| <= 8 * max|x| * 0.125 ~= 5.7 -> exp2 arg in [-1.03, 1.03]; denom >= 3.9: safe.
__device__ __forceinline__ float attn_one(const float vals[8], const f2 (&cs2)[8][4]) {
    f2 s2[4];
#pragma unroll
    for (int j = 0; j < 4; ++j) s2[j] = cs2[0][j] * vals[0];
#pragma unroll
    for (int k = 1; k < 8; ++k) {
        f2 vk = {vals[k], vals[k]};
#pragma unroll
        for (int j = 0; j < 4; ++j)
            s2[j] = __builtin_elementwise_fma(vk, cs2[k][j], s2[j]);
    }
    const float C = 0.18033688011112042f;   // log2(e)/8
    f2 C2 = {C, C};
    f2 sum2 = {0.f, 0.f}, num2 = {0.f, 0.f};
#pragma unroll
    for (int j = 0; j < 4; ++j) {
        f2 tt = s2[j] * C2;
        f2 e;
        e.x = __builtin_amdgcn_exp2f(tt.x);
        e.y = __builtin_amdgcn_exp2f(tt.y);
        sum2 += e;
        f2 v2 = {vals[2 * j], vals[2 * j + 1]};
        num2 = __builtin_elementwise_fma(v2, e, num2);
    }
    float sum = sum2.x + sum2.y;
    float num = num2.x + num2.y;
    return num * __builtin_amdgcn_rcpf(sum);
}

__device__ __forceinline__ void unpack2(const h4& a0, const h4& a1, float (&vals)[8]) {
    vals[0] = (float)a0.x; vals[1] = (float)a1.x;
    vals[2] = (float)a0.y; vals[3] = (float)a1.y;
    vals[4] = (float)a0.z; vals[5] = (float)a1.z;
    vals[6] = (float)a0.w; vals[7] = (float)a1.w;
}

// ---------------- fused gather + attn + softmax + weighted sum ----------------
// Block = one 64-v tile x one slice (1 b, 16 cgroups = one 128B line of each row).
// slice = bid & 7 -> pinned XCD under round-robin dispatch: per-XCD gather
// working set = 40962 * 128B = 5.25 MB ~ L2-resident.
template <int DIRECT>
__global__ __launch_bounds__(256) void fused_k(const _Float16* __restrict__ xsrc16,
                                               const float* __restrict__ xsrc32,
                                               const float* __restrict__ coeffs,
                                               const int* __restrict__ map,
                                               float* __restrict__ out) {
    __shared__ float otile[16][66];   // [cgroup][v]; write bank = (2cg+vs)%32 -> <=2-way
    __shared__ int   jmap[128];

    const int tid   = threadIdx.x;
    const int bid   = blockIdx.x;
    const int slice = bid & (NSLICE - 1);
    const int tile  = bid >> 3;
    const int vbase = tile * 64;
    const int b     = slice >> 2;
    const int c0    = (slice & 3) * 16;     // cgroup base (16 cgroups = 64 ch = 128B)
    const bool full = (vbase + 64 <= V_OUT);

    if (tid < 128) {
        int gi = vbase * 2 + tid;
        jmap[tid] = (gi < 2 * V_OUT) ? map[gi] : 0;
    }

    // wave-uniform coeff loads -> SGPRs
    f2 cs2[8][4];
#pragma unroll
    for (int k = 0; k < 8; ++k)
#pragma unroll
        for (int j = 0; j < 4; ++j)
            cs2[k][j] = *(const f2*)(coeffs + k * 8 + 2 * j);

    __syncthreads();

    const int w    = tid >> 6;
    const int lane = tid & 63;
    const int cg   = lane & 15;     // cgroup within slice; 16 lanes x 8B = one 128B line
    const int vs   = lane >> 4;     // v sub-slot 0..3

    const _Float16* xb = xsrc16 + (size_t)b * V_IN * CTOT + 4 * (c0 + cg);

    if (full && !DIRECT) {
#pragma unroll
        for (int i = 0; i < 4; ++i) {
            const int vl = w * 16 + 4 * i + vs;
            int2 jj = *(const int2*)&jmap[2 * vl];
            h4 a0 = *(const h4*)(xb + (size_t)jj.x * CTOT);
            h4 a1 = *(const h4*)(xb + (size_t)jj.y * CTOT);
            float vals[8];
            unpack2(a0, a1, vals);
            otile[cg][vl] = attn_one(vals, cs2);
        }
    } else {
        for (int i = 0; i < 4; ++i) {
            const int vl = w * 16 + 4 * i + vs;
            float r = 0.f;
            if (vbase + vl < V_OUT) {
                const int j0 = jmap[2 * vl];
                const int j1 = jmap[2 * vl + 1];
                float vals[8];
                if (DIRECT) {
#pragma unroll
                    for (int e = 0; e < 4; ++e) {
                        vals[2 * e]     = xsrc32[((size_t)b * CTOT + (c0 + cg) * 4 + e) * V_IN + j0];
                        vals[2 * e + 1] = xsrc32[((size_t)b * CTOT + (c0 + cg) * 4 + e) * V_IN + j1];
                    }
                } else {
                    h4 a0 = *(const h4*)(xb + (size_t)j0 * CTOT);
                    h4 a1 = *(const h4*)(xb + (size_t)j1 * CTOT);
                    unpack2(a0, a1, vals);
                }
                r = attn_one(vals, cs2);
            }
            otile[cg][vl] = r;
        }
    }
    __syncthreads();

    // ---------------- write-out: 16 rows x 64 v, f2 NT stores (r4-proven pattern) ----------------
    if (full) {
#pragma unroll
        for (int it = 0; it < 2; ++it) {
            const int r = (tid >> 5) + 8 * it;   // 0..15
            const int q = tid & 31;              // v pair index
            f2 val = {otile[r][2 * q], otile[r][2 * q + 1]};
            __builtin_nontemporal_store(val,
                (f2*)(out + ((size_t)b * NCH + c0 + r) * V_OUT + vbase + 2 * q));
        }
    } else {
#pragma unroll
        for (int it = 0; it < 2; ++it) {
            const int r = (tid >> 5) + 8 * it;
            const int q = tid & 31;
#pragma unroll
            for (int u = 0; u < 2; ++u) {
                int v = vbase + 2 * q + u;
                if (v < V_OUT)
                    out[((size_t)b * NCH + c0 + r) * V_OUT + v] = otile[r][2 * q + u];
            }
        }
    }
}

extern "C" void kernel_launch(void* const* d_in, const int* in_sizes, int n_in,
                              void* d_out, int out_size, void* d_ws, size_t ws_size,
                              hipStream_t stream) {
    const float* x      = (const float*)d_in[0];
    const float* coeffs = (const float*)d_in[1];
    const int*   map    = (const int*)d_in[2];
    float*       out    = (float*)d_out;

    const size_t xT_bytes = (size_t)2 * V_IN * CTOT * sizeof(_Float16);
    const int ntiles  = (V_OUT + 63) / 64;
    const int nblocks = ntiles * NSLICE;

    if (ws_size >= xT_bytes) {
        _Float16* xT = (_Float16*)d_ws;
        dim3 tgrid((V_IN + 63) / 64, CTOT / 64, 2);
        transpose_k<<<tgrid, dim3(256), 0, stream>>>(x, xT);
        fused_k<0><<<nblocks, 256, 0, stream>>>(xT, nullptr, coeffs, map, out);
    } else {
        fused_k<1><<<nblocks, 256, 0, stream>>>(nullptr, x, coeffs, map, out);
    }
}

// Round 10
// 89.960 us; speedup vs baseline: 1.8640x; 1.0405x over previous
//
#include <hip/hip_runtime.h>

#define V_IN 40962
#define V_OUT 163842
#define NCH 64
#define CTOT 256
#define NSLICE 8   // (b:2) x (channel-quarter:4); one slice per XCD via bid&7
#define CEXP 0.18033688011112042f   // log2(e)/8

typedef float    f2 __attribute__((ext_vector_type(2)));
typedef float    f4 __attribute__((ext_vector_type(4)));
typedef _Float16 h4 __attribute__((ext_vector_type(4)));

// ---------------- transpose+downcast + coeff prescale ----------------
__global__ __launch_bounds__(256) void transpose_k(const float* __restrict__ x,
                                                   _Float16* __restrict__ xT,
                                                   const float* __restrict__ coeffs,
                                                   float* __restrict__ scoef) {
    if (blockIdx.x == 0 && blockIdx.y == 0 && blockIdx.z == 0 && threadIdx.x < 64)
        scoef[threadIdx.x] = coeffs[threadIdx.x] * CEXP;

    __shared__ float tile[64][65];   // [v][c]
    const int b  = blockIdx.z;
    const int v0 = blockIdx.x * 64;
    const int c0 = blockIdx.y * 64;
    const int t  = threadIdx.x;
    const int i  = t & 15;
    const int s  = t >> 4;           // 0..15
#pragma unroll
    for (int p = 0; p < 4; ++p) {
        int c = s + 16 * p;
        int v = 4 * i;
        f4 val = {0.f, 0.f, 0.f, 0.f};
        const float* src = x + ((size_t)b * CTOT + c0 + c) * V_IN + v0 + v;
        if (v0 + v + 3 < V_IN) {
            val = __builtin_nontemporal_load((const f4*)src);
        } else {
            if (v0 + v     < V_IN) val.x = src[0];
            if (v0 + v + 1 < V_IN) val.y = src[1];
            if (v0 + v + 2 < V_IN) val.z = src[2];
            if (v0 + v + 3 < V_IN) val.w = src[3];
        }
        tile[v    ][c] = val.x;
        tile[v + 1][c] = val.y;
        tile[v + 2][c] = val.z;
        tile[v + 3][c] = val.w;
    }
    __syncthreads();
#pragma unroll
    for (int p = 0; p < 4; ++p) {
        int v = s + 16 * p;
        if (v0 + v < V_IN) {
            h4 val;
            val.x = (_Float16)tile[v][4 * i];
            val.y = (_Float16)tile[v][4 * i + 1];
            val.z = (_Float16)tile[v][4 * i + 2];
            val.w = (_Float16)tile[v][4 * i + 3];
            *(h4*)(xT + ((size_t)b * V_IN + v0 + v) * CTOT + c0 + 4 * i) = val;
        }
    }
}

// ---------------- attention math; cs2 is PRE-SCALED by log2(e)/8 ----------------
// |s| <= 5.7 -> exp2 arg in [-1.03,1.03], denom >= 3.9: no-max softmax is safe.
__device__ __forceinline__ float attn_one(const float vals[8], const f2 (&cs2)[8][4]) {
    f2 s2[4];
#pragma unroll
    for (int j = 0; j < 4; ++j) s2[j] = cs2[0][j] * vals[0];
#pragma unroll
    for (int k = 1; k < 8; ++k) {
        f2 vk = {vals[k], vals[k]};
#pragma unroll
        for (int j = 0; j < 4; ++j)
            s2[j] = __builtin_elementwise_fma(vk, cs2[k][j], s2[j]);
    }
    f2 sum2 = {0.f, 0.f}, num2 = {0.f, 0.f};
#pragma unroll
    for (int j = 0; j < 4; ++j) {
        f2 e;
        e.x = __builtin_amdgcn_exp2f(s2[j].x);
        e.y = __builtin_amdgcn_exp2f(s2[j].y);
        sum2 += e;
        f2 v2 = {vals[2 * j], vals[2 * j + 1]};
        num2 = __builtin_elementwise_fma(v2, e, num2);
    }
    return (num2.x + num2.y) * __builtin_amdgcn_rcpf(sum2.x + sum2.y);
}

__device__ __forceinline__ void unpack2(const h4& a0, const h4& a1, float (&vals)[8]) {
    vals[0] = (float)a0.x; vals[1] = (float)a1.x;
    vals[2] = (float)a0.y; vals[3] = (float)a1.y;
    vals[4] = (float)a0.z; vals[5] = (float)a1.z;
    vals[6] = (float)a0.w; vals[7] = (float)a1.w;
}

// ---------------- fused gather + attn + softmax + weighted sum ----------------
// Block = one 64-v tile x one slice (1 b, 16 cgroups = one 128B line per vertex row).
// lane (cg, g): cg = channel-group in slice, g -> 4 consecutive v.
template <int DIRECT>
__global__ __launch_bounds__(256) void fused_k(const _Float16* __restrict__ xsrc16,
                                               const float* __restrict__ xsrc32,
                                               const float* __restrict__ csrc,
                                               const int* __restrict__ map,
                                               float* __restrict__ out) {
    __shared__ float otile[16][66];

    const int tid   = threadIdx.x;
    const int bid   = blockIdx.x;
    const int slice = bid & (NSLICE - 1);
    const int tile  = bid >> 3;
    const int vbase = tile * 64;
    const int b     = slice >> 2;
    const int c0    = (slice & 3) * 16;
    const bool full = (vbase + 64 <= V_OUT);

    const int cg = tid & 15;
    const int g  = tid >> 4;         // 0..15
    const int v0 = vbase + 4 * g;

    // wave-uniform coeff loads -> SGPRs (pre-scaled for !DIRECT; scale here for DIRECT)
    f2 cs2[8][4];
#pragma unroll
    for (int k = 0; k < 8; ++k)
#pragma unroll
        for (int j = 0; j < 4; ++j) {
            f2 t = *(const f2*)(csrc + k * 8 + 2 * j);
            cs2[k][j] = DIRECT ? t * CEXP : t;
        }

    const _Float16* xb = xsrc16 + (size_t)b * V_IN * CTOT + 4 * (c0 + cg);
    const char*     xc = (const char*)xb;

    if (full && !DIRECT) {
        const int* mp = map + 2 * v0;
        int4 ja = *(const int4*)mp;
        int4 jb = *(const int4*)(mp + 4);
        // 8 gathers in flight before any compute
        h4 p0 = *(const h4*)(xc + ((size_t)(unsigned)ja.x << 9));
        h4 p1 = *(const h4*)(xc + ((size_t)(unsigned)ja.y << 9));
        h4 p2 = *(const h4*)(xc + ((size_t)(unsigned)ja.z << 9));
        h4 p3 = *(const h4*)(xc + ((size_t)(unsigned)ja.w << 9));
        h4 p4 = *(const h4*)(xc + ((size_t)(unsigned)jb.x << 9));
        h4 p5 = *(const h4*)(xc + ((size_t)(unsigned)jb.y << 9));
        h4 p6 = *(const h4*)(xc + ((size_t)(unsigned)jb.z << 9));
        h4 p7 = *(const h4*)(xc + ((size_t)(unsigned)jb.w << 9));
        float vals[8];
        unpack2(p0, p1, vals); float r0 = attn_one(vals, cs2);
        unpack2(p2, p3, vals); float r1 = attn_one(vals, cs2);
        unpack2(p4, p5, vals); float r2 = attn_one(vals, cs2);
        unpack2(p6, p7, vals); float r3 = attn_one(vals, cs2);
        f2 w0 = {r0, r1}, w1 = {r2, r3};
        *(f2*)&otile[cg][4 * g]     = w0;
        *(f2*)&otile[cg][4 * g + 2] = w1;
    } else {
#pragma unroll
        for (int i = 0; i < 4; ++i) {
            const int v = v0 + i;
            float r = 0.f;
            if (v < V_OUT) {
                const int j0 = map[2 * v];
                const int j1 = map[2 * v + 1];
                float vals[8];
                if (DIRECT) {
#pragma unroll
                    for (int e = 0; e < 4; ++e) {
                        vals[2 * e]     = xsrc32[((size_t)b * CTOT + (c0 + cg) * 4 + e) * V_IN + j0];
                        vals[2 * e + 1] = xsrc32[((size_t)b * CTOT + (c0 + cg) * 4 + e) * V_IN + j1];
                    }
                } else {
                    h4 a0 = *(const h4*)(xc + ((size_t)(unsigned)j0 << 9));
                    h4 a1 = *(const h4*)(xc + ((size_t)(unsigned)j1 << 9));
                    unpack2(a0, a1, vals);
                }
                r = attn_one(vals, cs2);
            }
            otile[cg][4 * g + i] = r;
        }
    }
    __syncthreads();

    // ---------------- write-out: 16 rows x 64 v, f2 NT stores (r9-proven) ----------------
    if (full) {
#pragma unroll
        for (int it = 0; it < 2; ++it) {
            const int r = (tid >> 5) + 8 * it;   // 0..15
            const int q = tid & 31;              // v pair index
            f2 val = {otile[r][2 * q], otile[r][2 * q + 1]};
            __builtin_nontemporal_store(val,
                (f2*)(out + ((size_t)b * NCH + c0 + r) * V_OUT + vbase + 2 * q));
        }
    } else {
#pragma unroll
        for (int it = 0; it < 2; ++it) {
            const int r = (tid >> 5) + 8 * it;
            const int q = tid & 31;
#pragma unroll
            for (int u = 0; u < 2; ++u) {
                int v = vbase + 2 * q + u;
                if (v < V_OUT)
                    out[((size_t)b * NCH + c0 + r) * V_OUT + v] = otile[r][2 * q + u];
            }
        }
    }
}

extern "C" void kernel_launch(void* const* d_in, const int* in_sizes, int n_in,
                              void* d_out, int out_size, void* d_ws, size_t ws_size,
                              hipStream_t stream) {
    const float* x      = (const float*)d_in[0];
    const float* coeffs = (const float*)d_in[1];
    const int*   map    = (const int*)d_in[2];
    float*       out    = (float*)d_out;

    const size_t xT_bytes = (size_t)2 * V_IN * CTOT * sizeof(_Float16);
    const int ntiles  = (V_OUT + 63) / 64;
    const int nblocks = ntiles * NSLICE;

    if (ws_size >= xT_bytes + 256) {
        _Float16* xT    = (_Float16*)d_ws;
        float*    scoef = (float*)((char*)d_ws + xT_bytes);
        dim3 tgrid((V_IN + 63) / 64, CTOT / 64, 2);
        transpose_k<<<tgrid, dim3(256), 0, stream>>>(x, xT, coeffs, scoef);
        fused_k<0><<<nblocks, 256, 0, stream>>>(xT, nullptr, scoef, map, out);
    } else {
        fused_k<1><<<nblocks, 256, 0, stream>>>(nullptr, x, coeffs, map, out);
    }
}

// Round 12
// 83.393 us; speedup vs baseline: 2.0108x; 1.0787x over previous
//
#include <hip/hip_runtime.h>

#define V_IN 40962
#define V_OUT 163842
#define NCH 64
#define CTOT 256
#define NSLICE 8   // (b:2) x (channel-quarter:4); one slice per XCD via bid&7
#define CEXP 0.18033688011112042f   // log2(e)/8

typedef float    f2 __attribute__((ext_vector_type(2)));
typedef float    f4 __attribute__((ext_vector_type(4)));
typedef _Float16 h2 __attribute__((ext_vector_type(2)));
typedef _Float16 h4 __attribute__((ext_vector_type(4)));
typedef __fp16   hv2 __attribute__((ext_vector_type(2)));   // type of cvt_pkrtz / fdot2 operands

#if defined(__has_builtin)
#if __has_builtin(__builtin_amdgcn_fdot2) && __has_builtin(__builtin_amdgcn_cvt_pkrtz)
#define USE_DOT2 1
#endif
#endif
#ifndef USE_DOT2
#define USE_DOT2 0
#endif

// ---------------- transpose+downcast + coeff prep (prescaled h2 k-pairs) ----------------
__global__ __launch_bounds__(256) void transpose_k(const float* __restrict__ x,
                                                   _Float16* __restrict__ xT,
                                                   const float* __restrict__ coeffs,
                                                   h2* __restrict__ scoefh) {
    if (blockIdx.x == 0 && blockIdx.y == 0 && blockIdx.z == 0 && threadIdx.x < 32) {
        const int f = threadIdx.x & 7, e = threadIdx.x >> 3;
        h2 v;
        v.x = (_Float16)(coeffs[(2 * e) * 8 + f] * CEXP);
        v.y = (_Float16)(coeffs[(2 * e + 1) * 8 + f] * CEXP);
        scoefh[e * 8 + f] = v;
    }

    __shared__ float tile[64][65];   // [v][c]
    const int b  = blockIdx.z;
    const int v0 = blockIdx.x * 64;
    const int c0 = blockIdx.y * 64;
    const int t  = threadIdx.x;
    const int i  = t & 15;
    const int s  = t >> 4;           // 0..15
#pragma unroll
    for (int p = 0; p < 4; ++p) {
        int c = s + 16 * p;
        int v = 4 * i;
        f4 val = {0.f, 0.f, 0.f, 0.f};
        const float* src = x + ((size_t)b * CTOT + c0 + c) * V_IN + v0 + v;
        if (v0 + v + 3 < V_IN) {
            val = __builtin_nontemporal_load((const f4*)src);
        } else {
            if (v0 + v     < V_IN) val.x = src[0];
            if (v0 + v + 1 < V_IN) val.y = src[1];
            if (v0 + v + 2 < V_IN) val.z = src[2];
            if (v0 + v + 3 < V_IN) val.w = src[3];
        }
        tile[v    ][c] = val.x;
        tile[v + 1][c] = val.y;
        tile[v + 2][c] = val.z;
        tile[v + 3][c] = val.w;
    }
    __syncthreads();
#pragma unroll
    for (int p = 0; p < 4; ++p) {
        int v = s + 16 * p;
        if (v0 + v < V_IN) {
            h4 val;
            val.x = (_Float16)tile[v][4 * i];
            val.y = (_Float16)tile[v][4 * i + 1];
            val.z = (_Float16)tile[v][4 * i + 2];
            val.w = (_Float16)tile[v][4 * i + 3];
            *(h4*)(xT + ((size_t)b * V_IN + v0 + v) * CTOT + c0 + 4 * i) = val;
        }
    }
}

// ---------------- f32 fallback attention (cs2 PRE-SCALED) ----------------
__device__ __forceinline__ float attn_one(const float vals[8], const f2 (&cs2)[8][4]) {
    f2 s2[4];
#pragma unroll
    for (int j = 0; j < 4; ++j) s2[j] = cs2[0][j] * vals[0];
#pragma unroll
    for (int k = 1; k < 8; ++k) {
        f2 vk = {vals[k], vals[k]};
#pragma unroll
        for (int j = 0; j < 4; ++j)
            s2[j] = __builtin_elementwise_fma(vk, cs2[k][j], s2[j]);
    }
    f2 sum2 = {0.f, 0.f}, num2 = {0.f, 0.f};
#pragma unroll
    for (int j = 0; j < 4; ++j) {
        f2 e;
        e.x = __builtin_amdgcn_exp2f(s2[j].x);
        e.y = __builtin_amdgcn_exp2f(s2[j].y);
        sum2 += e;
        f2 v2 = {vals[2 * j], vals[2 * j + 1]};
        num2 = __builtin_elementwise_fma(v2, e, num2);
    }
    return (num2.x + num2.y) * __builtin_amdgcn_rcpf(sum2.x + sum2.y);
}

__device__ __forceinline__ void unpack2(const h4& a0, const h4& a1, float (&vals)[8]) {
    vals[0] = (float)a0.x; vals[1] = (float)a1.x;
    vals[2] = (float)a0.y; vals[3] = (float)a1.y;
    vals[4] = (float)a0.z; vals[5] = (float)a1.z;
    vals[6] = (float)a0.w; vals[7] = (float)a1.w;
}

#if USE_DOT2
// ---------------- fp16-dot2 attention: vals consumed packed, no unpack cvts ----------------
// cs[e][f] = {C[2e][f], C[2e+1][f]} * log2(e)/8, fp16.  |exp2 arg| <= 1.03: no-max safe.
__device__ __forceinline__ float attn_dot2(const h4 p0, const h4 p1, const hv2 (&cs)[4][8]) {
    hv2 vp[4];
    h2 t0; t0.x = p0.x; t0.y = p1.x; vp[0] = __builtin_bit_cast(hv2, t0);
    h2 t1; t1.x = p0.y; t1.y = p1.y; vp[1] = __builtin_bit_cast(hv2, t1);
    h2 t2; t2.x = p0.z; t2.y = p1.z; vp[2] = __builtin_bit_cast(hv2, t2);
    h2 t3; t3.x = p0.w; t3.y = p1.w; vp[3] = __builtin_bit_cast(hv2, t3);
    float s[8];
#pragma unroll
    for (int f = 0; f < 8; ++f) {
        float acc = __builtin_amdgcn_fdot2(vp[0], cs[0][f], 0.f, false);
        acc = __builtin_amdgcn_fdot2(vp[1], cs[1][f], acc, false);
        acc = __builtin_amdgcn_fdot2(vp[2], cs[2][f], acc, false);
        s[f] = __builtin_amdgcn_fdot2(vp[3], cs[3][f], acc, false);
    }
    float e[8];
#pragma unroll
    for (int f = 0; f < 8; ++f) e[f] = __builtin_amdgcn_exp2f(s[f]);
    hv2 eh[4];
#pragma unroll
    for (int j = 0; j < 4; ++j) eh[j] = __builtin_amdgcn_cvt_pkrtz(e[2 * j], e[2 * j + 1]);
    hv2 ones; ones.x = (__fp16)1.f; ones.y = (__fp16)1.f;
    float sum = 0.f, num = 0.f;
#pragma unroll
    for (int j = 0; j < 4; ++j) {
        sum = __builtin_amdgcn_fdot2(eh[j], ones, sum, false);
        num = __builtin_amdgcn_fdot2(vp[j], eh[j], num, false);
    }
    return num * __builtin_amdgcn_rcpf(sum);
}
#endif

// ---------------- fused gather + attn + softmax + weighted sum ----------------
// Block = one 64-v tile x one slice (1 b, 16 cgroups = one 128B line per vertex row).
template <int DIRECT>
__global__ __launch_bounds__(256) void fused_k(const _Float16* __restrict__ xsrc16,
                                               const float* __restrict__ xsrc32,
                                               const void* __restrict__ csrc,
                                               const int* __restrict__ map,
                                               float* __restrict__ out) {
    __shared__ float otile[16][66];

    const int tid   = threadIdx.x;
    const int bid   = blockIdx.x;
    const int slice = bid & (NSLICE - 1);
    const int tile  = bid >> 3;
    const int vbase = tile * 64;
    const int b     = slice >> 2;
    const int c0    = (slice & 3) * 16;
    const bool full = (vbase + 64 <= V_OUT);

    const int cg = tid & 15;
    const int g  = tid >> 4;         // 0..15
    const int v0 = vbase + 4 * g;

#if USE_DOT2
    hv2 csh[4][8];
    if (!DIRECT) {
        const h2* ch = (const h2*)csrc;
#pragma unroll
        for (int e = 0; e < 4; ++e)
#pragma unroll
            for (int f = 0; f < 8; ++f) csh[e][f] = __builtin_bit_cast(hv2, ch[e * 8 + f]);
    }
#endif
    f2 cs2[8][4];
#if USE_DOT2
    if (DIRECT)
#endif
    {
        const float* cf = (const float*)csrc;
#pragma unroll
        for (int k = 0; k < 8; ++k)
#pragma unroll
            for (int j = 0; j < 4; ++j) {
                f2 t = *(const f2*)(cf + k * 8 + 2 * j);
                cs2[k][j] = DIRECT ? t * CEXP : t;
            }
    }

    const char* xs = (const char*)(xsrc16 + (size_t)b * V_IN * CTOT + 4 * c0);
    const unsigned cg8 = (unsigned)cg << 3;

    if (full && !DIRECT) {
        const int* mp = map + 2 * v0;
        int4 ja = *(const int4*)mp;
        int4 jb = *(const int4*)(mp + 4);
        h4 p0 = *(const h4*)(xs + (((unsigned)ja.x << 9) | cg8));
        h4 p1 = *(const h4*)(xs + (((unsigned)ja.y << 9) | cg8));
        h4 p2 = *(const h4*)(xs + (((unsigned)ja.z << 9) | cg8));
        h4 p3 = *(const h4*)(xs + (((unsigned)ja.w << 9) | cg8));
        h4 p4 = *(const h4*)(xs + (((unsigned)jb.x << 9) | cg8));
        h4 p5 = *(const h4*)(xs + (((unsigned)jb.y << 9) | cg8));
        h4 p6 = *(const h4*)(xs + (((unsigned)jb.z << 9) | cg8));
        h4 p7 = *(const h4*)(xs + (((unsigned)jb.w << 9) | cg8));
        float r0, r1, r2, r3;
#if USE_DOT2
        r0 = attn_dot2(p0, p1, csh);
        r1 = attn_dot2(p2, p3, csh);
        r2 = attn_dot2(p4, p5, csh);
        r3 = attn_dot2(p6, p7, csh);
#else
        float vals[8];
        unpack2(p0, p1, vals); r0 = attn_one(vals, cs2);
        unpack2(p2, p3, vals); r1 = attn_one(vals, cs2);
        unpack2(p4, p5, vals); r2 = attn_one(vals, cs2);
        unpack2(p6, p7, vals); r3 = attn_one(vals, cs2);
#endif
        f2 w0 = {r0, r1}, w1 = {r2, r3};
        *(f2*)&otile[cg][4 * g]     = w0;
        *(f2*)&otile[cg][4 * g + 2] = w1;
    } else {
#pragma unroll
        for (int i = 0; i < 4; ++i) {
            const int v = v0 + i;
            float r = 0.f;
            if (v < V_OUT) {
                const int j0 = map[2 * v];
                const int j1 = map[2 * v + 1];
                if (DIRECT) {
                    float vals[8];
#pragma unroll
                    for (int e = 0; e < 4; ++e) {
                        vals[2 * e]     = xsrc32[((size_t)b * CTOT + (c0 + cg) * 4 + e) * V_IN + j0];
                        vals[2 * e + 1] = xsrc32[((size_t)b * CTOT + (c0 + cg) * 4 + e) * V_IN + j1];
                    }
                    r = attn_one(vals, cs2);
                } else {
                    h4 a0 = *(const h4*)(xs + (((unsigned)j0 << 9) | cg8));
                    h4 a1 = *(const h4*)(xs + (((unsigned)j1 << 9) | cg8));
#if USE_DOT2
                    r = attn_dot2(a0, a1, csh);
#else
                    float vals[8];
                    unpack2(a0, a1, vals);
                    r = attn_one(vals, cs2);
#endif
                }
            }
            otile[cg][4 * g + i] = r;
        }
    }
    __syncthreads();

    // ---------------- write-out: 16 rows x 64 v, f2 NT stores (r9/r10-proven) ----------------
    if (full) {
#pragma unroll
        for (int it = 0; it < 2; ++it) {
            const int r = (tid >> 5) + 8 * it;   // 0..15
            const int q = tid & 31;              // v pair index
            f2 val = {otile[r][2 * q], otile[r][2 * q + 1]};
            __builtin_nontemporal_store(val,
                (f2*)(out + ((size_t)b * NCH + c0 + r) * V_OUT + vbase + 2 * q));
        }
    } else {
#pragma unroll
        for (int it = 0; it < 2; ++it) {
            const int r = (tid >> 5) + 8 * it;
            const int q = tid & 31;
#pragma unroll
            for (int u = 0; u < 2; ++u) {
                int v = vbase + 2 * q + u;
                if (v < V_OUT)
                    out[((size_t)b * NCH + c0 + r) * V_OUT + v] = otile[r][2 * q + u];
            }
        }
    }
}

extern "C" void kernel_launch(void* const* d_in, const int* in_sizes, int n_in,
                              void* d_out, int out_size, void* d_ws, size_t ws_size,
                              hipStream_t stream) {
    const float* x      = (const float*)d_in[0];
    const float* coeffs = (const float*)d_in[1];
    const int*   map    = (const int*)d_in[2];
    float*       out    = (float*)d_out;

    const size_t xT_bytes = (size_t)2 * V_IN * CTOT * sizeof(_Float16);
    const int ntiles  = (V_OUT + 63) / 64;
    const int nblocks = ntiles * NSLICE;

    if (ws_size >= xT_bytes + 128) {
        _Float16* xT    = (_Float16*)d_ws;
        h2*       scoef = (h2*)((char*)d_ws + xT_bytes);
        dim3 tgrid((V_IN + 63) / 64, CTOT / 64, 2);
        transpose_k<<<tgrid, dim3(256), 0, stream>>>(x, xT, coeffs, scoef);
        fused_k<0><<<nblocks, 256, 0, stream>>>(xT, nullptr, scoef, map, out);
    } else {
        fused_k<1><<<nblocks, 256, 0, stream>>>(nullptr, x, coeffs, map, out);
    }
}